// Round 3
// baseline (189.847 us; speedup 1.0000x reference)
//
#include <hip/hip_runtime.h>
#include <stdint.h>

// Problem constants (match reference)
#define B_ 4096
#define C_ 200
#define P_ 32
#define F_ 512
#define N_ (C_*P_)        // 6400 prototypes total
#define ALPHA_ 5.0
#define EPS_ 1e-8

typedef unsigned char u8;
typedef __attribute__((ext_vector_type(8))) int int8v;      // 8 VGPRs: fp8 A/B frag (32 bytes)
typedef __attribute__((ext_vector_type(4))) float floatx4;  // MFMA C/D frag

union frag32 { int8v v; int4 q[2]; };

// ---------- prep: fp32 -> fp8 e4m3 rows, plus p2 for cluster rows ----------
// One wave per row. Rows [0,B) = outputs -> A8. Rows [B, B+N) = clusters -> B8 (+p2).
__global__ void prep_kernel(const float* __restrict__ outputs, const float* __restrict__ clusters,
                            u8* __restrict__ A8, u8* __restrict__ B8, float* __restrict__ p2) {
    int row  = blockIdx.x * 4 + (threadIdx.x >> 6);
    int lane = threadIdx.x & 63;
    const float* src; u8* dst; bool isB;
    if (row < B_) { src = outputs + (size_t)row * F_;        dst = A8 + (size_t)row * F_;        isB = false; }
    else          { src = clusters + (size_t)(row - B_) * F_; dst = B8 + (size_t)(row - B_) * F_; isB = true; }
    float4 v0 = ((const float4*)src)[lane * 2];
    float4 v1 = ((const float4*)src)[lane * 2 + 1];
    int lo = __builtin_amdgcn_cvt_pk_fp8_f32(v0.x, v0.y, 0, false);
    lo     = __builtin_amdgcn_cvt_pk_fp8_f32(v0.z, v0.w, lo, true);
    int hi = __builtin_amdgcn_cvt_pk_fp8_f32(v1.x, v1.y, 0, false);
    hi     = __builtin_amdgcn_cvt_pk_fp8_f32(v1.z, v1.w, hi, true);
    ((int2*)dst)[lane] = make_int2(lo, hi);
    if (isB) {
        float s = v0.x*v0.x + v0.y*v0.y + v0.z*v0.z + v0.w*v0.w
                + v1.x*v1.x + v1.y*v1.y + v1.z*v1.z + v1.w*v1.w;
#pragma unroll
        for (int m = 32; m >= 1; m >>= 1) s += __shfl_xor(s, m);
        if (lane == 0) p2[row - B_] = s;
    }
}

// ---------- score kernel: MX-fp8 MFMA GEMM (K=128/stage) + fused per-class min/argmin ----------
#define BM 128
#define BN 128
#define BK 128   // fp8 bytes per row per stage; F_/BK = 4 stages

typedef const __attribute__((address_space(1))) unsigned int gu32_t;
typedef __attribute__((address_space(3))) unsigned int lu32_t;

__device__ __forceinline__ void gld16(const u8* g, u8* l) {
    // async global->LDS, 16B per lane; LDS dest is wave-uniform base + lane*16
    __builtin_amdgcn_global_load_lds((gu32_t*)g, (lu32_t*)l, 16, 0, 0);
}

__global__ __launch_bounds__(256)
void score_kernel(const u8* __restrict__ A8, const u8* __restrict__ B8,
                  const float* __restrict__ p2,
                  float* __restrict__ min_d, int* __restrict__ min_idx) {
    // 16 KB each; rows of 128 B, 16B-chunks XOR-swizzled: LDS[row][c] = global chunk (c ^ (row&7))
    __shared__ __align__(16) u8 sA[BM * BK];
    __shared__ __align__(16) u8 sB[BN * BK];

    const int tid  = threadIdx.x;
    const int lane = tid & 63;
    const int w    = tid >> 6;          // wave 0..3
    const int wm   = w >> 1, wn = w & 1;
    const int bx   = blockIdx.x;        // n-tile 0..49
    const int by   = blockIdx.y;        // m-tile 0..31
    const int m0   = by * BM, n0 = bx * BN;
    const int mrow = lane & 15;         // M/N index within a 16x16 MFMA tile
    const int quad = lane >> 4;         // 0..3
    // staging: one gld16 = 1KB = 8 rows x 128B. lane -> (srow, chunk lane&7)
    const int srow  = lane >> 3;                       // 0..7 (row within 8-row group)
    const int scolg = ((lane & 7) ^ srow) * 16;        // swizzled SOURCE col so LDS[r][c]=glob c^ (r&7)
    // frag-read chunk offsets (per-lane constant): global chunks quad*2, quad*2+1, swizzled by row&7==mrow&7
    const int c0 = (((quad * 2)     ^ (mrow & 7)) * 16);
    const int c1 = (((quad * 2 + 1) ^ (mrow & 7)) * 16);

    floatx4 zf = {0.f, 0.f, 0.f, 0.f};
    floatx4 acc[4][4];
#pragma unroll
    for (int i = 0; i < 4; ++i)
#pragma unroll
        for (int j = 0; j < 4; ++j) acc[i][j] = zf;

#pragma unroll
    for (int kt = 0; kt < F_ / BK; ++kt) {
        const int k0 = kt * BK;
        __syncthreads();  // previous stage's ds_reads done before overwrite
#pragma unroll
        for (int i = 0; i < 4; ++i) {
            int r0 = w * 32 + i * 8;    // wave-uniform 8-row group
            gld16(A8 + (size_t)(m0 + r0 + srow) * F_ + k0 + scolg, sA + r0 * BK);
            gld16(B8 + (size_t)(n0 + r0 + srow) * F_ + k0 + scolg, sB + r0 * BK);
        }
        __syncthreads();  // drain global_load_lds (vmcnt) + barrier

        frag32 af[4], bf[4];
#pragma unroll
        for (int t = 0; t < 4; ++t) {
            const u8* pa = sA + (wm * 64 + t * 16 + mrow) * BK;
            af[t].q[0] = *(const int4*)(pa + c0);
            af[t].q[1] = *(const int4*)(pa + c1);
            const u8* pb = sB + (wn * 64 + t * 16 + mrow) * BK;
            bf[t].q[0] = *(const int4*)(pb + c0);
            bf[t].q[1] = *(const int4*)(pb + c1);
        }
#pragma unroll
        for (int mt = 0; mt < 4; ++mt)
#pragma unroll
            for (int nt = 0; nt < 4; ++nt)
                acc[mt][nt] = __builtin_amdgcn_mfma_scale_f32_16x16x128_f8f6f4(
                    af[mt].v, bf[nt].v, acc[mt][nt],
                    0, 0,                 // cbsz=fp8(e4m3), blgp=fp8(e4m3)
                    0, 0x7f7f7f7f,        // opselA, scaleA = 1.0 (E8M0 127)
                    0, 0x7f7f7f7f);       // opselB, scaleB = 1.0
    }

    // Epilogue: score = p2[n] - 2*xp (x2 dropped: constant per row b, argmins unchanged).
    // C/D layout (shape-determined): col = lane&15, row = quad*4 + reg. Each wave: 64 rows x 2 classes.
    float pg[4];
#pragma unroll
    for (int nt = 0; nt < 4; ++nt) pg[nt] = p2[n0 + wn * 64 + nt * 16 + mrow];

#pragma unroll
    for (int ch = 0; ch < 2; ++ch) {
        const int cls = bx * 4 + wn * 2 + ch;
#pragma unroll
        for (int mt = 0; mt < 4; ++mt)
#pragma unroll
            for (int reg = 0; reg < 4; ++reg) {
                float v0 = pg[ch * 2]     - 2.0f * acc[mt][ch * 2][reg];     // p = mrow
                float v1 = pg[ch * 2 + 1] - 2.0f * acc[mt][ch * 2 + 1][reg]; // p = 16+mrow
                float v; int pi;
                if (v1 < v0) { v = v1; pi = 16 + mrow; } else { v = v0; pi = mrow; }
#pragma unroll
                for (int m = 8; m >= 1; m >>= 1) {
                    float ov = __shfl_xor(v, m);
                    int   oi = __shfl_xor(pi, m);
                    if (ov < v || (ov == v && oi < pi)) { v = ov; pi = oi; }
                }
                if (mrow == 0) {
                    int grow = m0 + wm * 64 + mt * 16 + quad * 4 + reg;
                    min_d[grow * C_ + cls]   = v;
                    min_idx[grow * C_ + cls] = pi;
                }
            }
    }
}

// ---------- per-sample selection + exact fp32 distances (no atomics) ----------
__global__ void select_kernel(const float* __restrict__ X, const float* __restrict__ clusters,
                              const int* __restrict__ tgt, const float* __restrict__ min_d,
                              const int* __restrict__ min_idx,
                              float* __restrict__ stw, float* __restrict__ sww) {
    int b    = blockIdx.x * 4 + (threadIdx.x >> 6);
    int lane = threadIdx.x & 63;
    int tc   = tgt[b];

    float bv = 3.4e38f; int bc = 1 << 30;
    for (int c = lane; c < C_; c += 64) {
        float v = min_d[b * C_ + c];
        if (c != tc && (v < bv || (v == bv && c < bc))) { bv = v; bc = c; }
    }
#pragma unroll
    for (int m = 32; m >= 1; m >>= 1) {
        float ov = __shfl_xor(bv, m);
        int   oc = __shfl_xor(bc, m);
        if (ov < bv || (ov == bv && oc < bc)) { bv = ov; bc = oc; }
    }
    int ap = min_idx[b * C_ + tc];   // best proto in target class
    int wp = min_idx[b * C_ + bc];   // best proto in nearest wrong class

    const float4* xb = (const float4*)(X + (size_t)b * F_);
    const float4* pa = (const float4*)(clusters + ((size_t)tc * P_ + ap) * F_);
    const float4* pw = (const float4*)(clusters + ((size_t)bc * P_ + wp) * F_);
    float st = 0.f, sw = 0.f;
#pragma unroll
    for (int i = 0; i < 2; ++i) {
        float4 x = xb[lane + i * 64], a = pa[lane + i * 64], ww = pw[lane + i * 64];
        float dx = x.x - a.x, dy = x.y - a.y, dz = x.z - a.z, dw = x.w - a.w;
        st += dx*dx + dy*dy + dz*dz + dw*dw;
        dx = x.x - ww.x; dy = x.y - ww.y; dz = x.z - ww.z; dw = x.w - ww.w;
        sw += dx*dx + dy*dy + dz*dz + dw*dw;
    }
#pragma unroll
    for (int m = 32; m >= 1; m >>= 1) { st += __shfl_xor(st, m); sw += __shfl_xor(sw, m); }
    if (lane == 0) { stw[b] = st; sww[b] = sw; }
}

// Single-block reduction of 2x4096 floats + final loss
__global__ __launch_bounds__(1024)
void finalize_kernel(const float* __restrict__ stw, const float* __restrict__ sww,
                     float* __restrict__ out) {
    __shared__ float r1[16], r2[16];
    int tid = threadIdx.x;
    float s1 = 0.f, s2 = 0.f;
#pragma unroll
    for (int i = 0; i < 4; ++i) {
        s1 += stw[tid + i * 1024];
        s2 += sww[tid + i * 1024];
    }
#pragma unroll
    for (int m = 32; m >= 1; m >>= 1) { s1 += __shfl_xor(s1, m); s2 += __shfl_xor(s2, m); }
    if ((tid & 63) == 0) { r1[tid >> 6] = s1; r2[tid >> 6] = s2; }
    __syncthreads();
    if (tid == 0) {
        double t1 = 0.0, t2 = 0.0;
#pragma unroll
        for (int i = 0; i < 16; ++i) { t1 += (double)r1[i]; t2 += (double)r2[i]; }
        double denom = (double)B_ * (double)F_;
        double tl  = t1 / denom;
        double ntl = t2 / denom;
        out[0] = (float)((1.0 - ALPHA_) * tl + ALPHA_ / (ntl + EPS_));
    }
}

// ---------- launch ----------
extern "C" void kernel_launch(void* const* d_in, const int* in_sizes, int n_in,
                              void* d_out, int out_size, void* d_ws, size_t ws_size,
                              hipStream_t stream) {
    const float* outputs  = (const float*)d_in[0];
    const float* clusters = (const float*)d_in[1];
    const int*   tgt      = (const int*)d_in[2];
    float* out = (float*)d_out;

    char* ws = (char*)d_ws;
    // workspace layout (16B-aligned), total 11,953,152 bytes
    u8*     A8      = (u8*)(ws);                     // 4096*512    = 2,097,152
    u8*     B8      = (u8*)(ws + 2097152);           // 6400*512    = 3,276,800
    float*  p2      = (float*)(ws + 5373952);        // 6400*4      =    25,600
    float*  min_d   = (float*)(ws + 5399552);        // 4096*200*4  = 3,276,800
    int*    min_idx = (int*)(ws + 8676352);          // 4096*200*4  = 3,276,800
    // per-sample partials: reuse the A8 region (dead after score_kernel)
    float*  stw     = (float*)(ws);                  // 4096*4 = 16 KB
    float*  sww     = (float*)(ws + 16384);          // 4096*4 = 16 KB

    prep_kernel<<<(B_ + N_) / 4, 256, 0, stream>>>(outputs, clusters, A8, B8, p2);   // 2624 blocks
    score_kernel<<<dim3(N_ / BN, B_ / BM), 256, 0, stream>>>(A8, B8, p2, min_d, min_idx);
    select_kernel<<<B_ / 4, 256, 0, stream>>>(outputs, clusters, tgt, min_d, min_idx, stw, sww);
    finalize_kernel<<<1, 1024, 0, stream>>>(stw, sww, out);
}